// Round 1
// baseline (766.157 us; speedup 1.0000x reference)
//
#include <hip/hip_runtime.h>
#include <hip/hip_bf16.h>

#define TT 200
#define UU 50
#define BB 8
#define DJ 1024   // D_JOINT
#define DE 512    // D_ENC / D_DEC
#define VV 1024
#define M_TOTAL (BB*TT*UU)   // 80000

typedef __bf16 bf16x8 __attribute__((ext_vector_type(8)));
typedef float f32x4 __attribute__((ext_vector_type(4)));
typedef unsigned short ushort8 __attribute__((ext_vector_type(8)));

__device__ __forceinline__ unsigned short f2bf(float f) {
    union { float f; unsigned u; } v; v.f = f;
    unsigned r = v.u + 0x7FFFu + ((v.u >> 16) & 1u);   // RNE
    return (unsigned short)(r >> 16);
}

__device__ __forceinline__ float fast_tanh(float x) {
    // tanh(x) = 1 - 2/(e^{2x}+1); exact limits at +-inf, error ~1e-6 << bf16 quant
    float e = __expf(2.f * x);
    return 1.f - 2.f / (e + 1.f);
}

// ---------- kernel 1: W_fc fp32 -> bf16 ----------
__global__ void k_wfc_bf16(const float* __restrict__ w, unsigned short* __restrict__ o) {
    int i = (blockIdx.x * 256 + threadIdx.x) * 8;
    float4 a = *(const float4*)(w + i);
    float4 b = *(const float4*)(w + i + 4);
    ushort8 h;
    h[0] = f2bf(a.x); h[1] = f2bf(a.y); h[2] = f2bf(a.z); h[3] = f2bf(a.w);
    h[4] = f2bf(b.x); h[5] = f2bf(b.y); h[6] = f2bf(b.z); h[7] = f2bf(b.w);
    *(ushort8*)(o + i) = h;
}

// ---------- kernel 2: projection  out[m][j] = sum_d in[m][d]*W[j][d] + b[j] ----------
// grid: (Mrows/16, 4), block 256.  W is (1024, 512) row-major.
__global__ __launch_bounds__(256) void k_proj(const float* __restrict__ in,
                                              const float* __restrict__ W,
                                              const float* __restrict__ bias,
                                              float* __restrict__ out) {
    __shared__ float in_s[16][DE];   // 32 KB
    const int m0 = blockIdx.x * 16;
    const int tid = threadIdx.x;
    #pragma unroll
    for (int it = 0; it < 8; ++it) {
        int idx = tid + it * 256;           // float4 index into [16][128]
        int r = idx >> 7, c = (idx & 127) << 2;
        *(float4*)&in_s[r][c] = *(const float4*)(in + (size_t)(m0 + r) * DE + c);
    }
    __syncthreads();
    const int j = blockIdx.y * 256 + tid;
    const float4* wr = (const float4*)(W + (size_t)j * DE);
    float acc[16];
    #pragma unroll
    for (int r = 0; r < 16; ++r) acc[r] = 0.f;
    for (int d4 = 0; d4 < DE / 4; ++d4) {
        float4 w = wr[d4];
        #pragma unroll
        for (int r = 0; r < 16; ++r) {
            float4 x = *(const float4*)&in_s[r][d4 << 2];
            acc[r] += x.x * w.x + x.y * w.y + x.z * w.z + x.w * w.w;
        }
    }
    float bv = bias[j];
    #pragma unroll
    for (int r = 0; r < 16; ++r)
        out[(size_t)(m0 + r) * DJ + j] = acc[r] + bv;
}

// ---------- kernel 3: fused  tanh(enc+dec) @ W_fc^T + b_fc -> log_softmax ----------
// block = 32 M-rows x full N=1024, 256 threads (4 waves), wave w owns N-chunk [256w,256w+256)
__global__ __launch_bounds__(256, 2) void k_joint(const float* __restrict__ encp,
                                                  const float* __restrict__ decp,
                                                  const unsigned short* __restrict__ wfc,
                                                  const float* __restrict__ bfc,
                                                  float* __restrict__ out) {
    __shared__ unsigned short A_s[32][DJ];   // 64 KB, XOR-swizzled in col
    __shared__ float red[4][32];
    const int tid = threadIdx.x;
    const int m0 = blockIdx.x * 32;

    // ---- stage A = tanh(enc_row + dec_row) as bf16, swizzled ----
    {
        const int row = tid >> 3;            // 32 rows x 8 threads/row
        const int m = m0 + row;
        const int b = m / (TT * UU);
        const int rem = m - b * (TT * UU);
        const int t = rem / UU;
        const int u = rem - t * UU;
        const float* er = encp + (size_t)(b * TT + t) * DJ;
        const float* dr = decp + (size_t)(b * UU + u) * DJ;
        const int c0 = (tid & 7) * 128;
        const int sw = (row & 7) << 3;
        for (int i = 0; i < 128; i += 8) {
            const int c = c0 + i;
            float4 e0 = *(const float4*)(er + c);
            float4 e1 = *(const float4*)(er + c + 4);
            float4 d0 = *(const float4*)(dr + c);
            float4 d1 = *(const float4*)(dr + c + 4);
            ushort8 h;
            h[0] = f2bf(fast_tanh(e0.x + d0.x)); h[1] = f2bf(fast_tanh(e0.y + d0.y));
            h[2] = f2bf(fast_tanh(e0.z + d0.z)); h[3] = f2bf(fast_tanh(e0.w + d0.w));
            h[4] = f2bf(fast_tanh(e1.x + d1.x)); h[5] = f2bf(fast_tanh(e1.y + d1.y));
            h[6] = f2bf(fast_tanh(e1.z + d1.z)); h[7] = f2bf(fast_tanh(e1.w + d1.w));
            *(ushort8*)&A_s[row][c ^ sw] = h;
        }
    }
    __syncthreads();

    // ---- GEMM: per wave, 2 M-tiles x 16 N-tiles, K=1024 ----
    const int wave = tid >> 6, lane = tid & 63;
    const int g = lane >> 4, ln = lane & 15;
    const int nw = wave * 256;
    const int asw = (ln & 7) << 3;

    f32x4 acc[2][16];
    #pragma unroll
    for (int mt = 0; mt < 2; ++mt)
        #pragma unroll
        for (int nt = 0; nt < 16; ++nt)
            acc[mt][nt] = (f32x4){0.f, 0.f, 0.f, 0.f};

    for (int k0 = 0; k0 < DJ; k0 += 32) {
        const int kk = k0 + g * 8;
        bf16x8 a0 = *(const bf16x8*)&A_s[ln][kk ^ asw];
        bf16x8 a1 = *(const bf16x8*)&A_s[16 + ln][kk ^ asw];
        #pragma unroll
        for (int nt = 0; nt < 16; ++nt) {
            const int n = nw + nt * 16 + ln;
            bf16x8 bfr = *(const bf16x8*)(wfc + (size_t)n * DJ + kk);
            acc[0][nt] = __builtin_amdgcn_mfma_f32_16x16x32_bf16(a0, bfr, acc[0][nt], 0, 0, 0);
            acc[1][nt] = __builtin_amdgcn_mfma_f32_16x16x32_bf16(a1, bfr, acc[1][nt], 0, 0, 0);
        }
    }

    // ---- fused log_softmax over N=1024 ----
    float bv[16];
    #pragma unroll
    for (int nt = 0; nt < 16; ++nt) bv[nt] = bfc[nw + nt * 16 + ln];

    // pass 1: row max
    float rmax[2][4];
    #pragma unroll
    for (int mt = 0; mt < 2; ++mt)
        #pragma unroll
        for (int r = 0; r < 4; ++r) {
            float mx = -3.0e38f;
            #pragma unroll
            for (int nt = 0; nt < 16; ++nt) mx = fmaxf(mx, acc[mt][nt][r] + bv[nt]);
            #pragma unroll
            for (int s = 1; s < 16; s <<= 1) mx = fmaxf(mx, __shfl_xor(mx, s));
            rmax[mt][r] = mx;
        }
    if (ln == 0) {
        #pragma unroll
        for (int mt = 0; mt < 2; ++mt)
            #pragma unroll
            for (int r = 0; r < 4; ++r) red[wave][mt * 16 + g * 4 + r] = rmax[mt][r];
    }
    __syncthreads();
    #pragma unroll
    for (int mt = 0; mt < 2; ++mt)
        #pragma unroll
        for (int r = 0; r < 4; ++r) {
            const int row = mt * 16 + g * 4 + r;
            rmax[mt][r] = fmaxf(fmaxf(red[0][row], red[1][row]), fmaxf(red[2][row], red[3][row]));
        }
    __syncthreads();

    // pass 2: sum of exp
    float rsum[2][4];
    #pragma unroll
    for (int mt = 0; mt < 2; ++mt)
        #pragma unroll
        for (int r = 0; r < 4; ++r) {
            float s = 0.f;
            #pragma unroll
            for (int nt = 0; nt < 16; ++nt) s += __expf(acc[mt][nt][r] + bv[nt] - rmax[mt][r]);
            #pragma unroll
            for (int t2 = 1; t2 < 16; t2 <<= 1) s += __shfl_xor(s, t2);
            rsum[mt][r] = s;
        }
    if (ln == 0) {
        #pragma unroll
        for (int mt = 0; mt < 2; ++mt)
            #pragma unroll
            for (int r = 0; r < 4; ++r) red[wave][mt * 16 + g * 4 + r] = rsum[mt][r];
    }
    __syncthreads();

    #pragma unroll
    for (int mt = 0; mt < 2; ++mt)
        #pragma unroll
        for (int r = 0; r < 4; ++r) {
            const int row = mt * 16 + g * 4 + r;
            const float S = red[0][row] + red[1][row] + red[2][row] + red[3][row];
            const float lg = rmax[mt][r] + __logf(S);
            float* op = out + (size_t)(m0 + row) * VV + nw + ln;
            #pragma unroll
            for (int nt = 0; nt < 16; ++nt)
                op[nt * 16] = acc[mt][nt][r] + bv[nt] - lg;
        }
}

extern "C" void kernel_launch(void* const* d_in, const int* in_sizes, int n_in,
                              void* d_out, int out_size, void* d_ws, size_t ws_size,
                              hipStream_t stream) {
    const float* enc   = (const float*)d_in[0];
    const float* dec   = (const float*)d_in[1];
    const float* W_enc = (const float*)d_in[2];
    const float* b_enc = (const float*)d_in[3];
    const float* W_dec = (const float*)d_in[4];
    const float* b_dec = (const float*)d_in[5];
    const float* W_fc  = (const float*)d_in[6];
    const float* b_fc  = (const float*)d_in[7];
    float* out = (float*)d_out;

    float* encp = (float*)d_ws;                              // 1600*1024 f32 = 6.55 MB
    float* decp = encp + (size_t)BB * TT * DJ;               //  400*1024 f32 = 1.64 MB
    unsigned short* wfcb = (unsigned short*)(decp + (size_t)BB * UU * DJ);  // 2 MB bf16

    k_wfc_bf16<<<(VV * DJ) / (256 * 8), 256, 0, stream>>>(W_fc, wfcb);
    k_proj<<<dim3((BB * TT) / 16, DJ / 256), 256, 0, stream>>>(enc, W_enc, b_enc, encp);
    k_proj<<<dim3((BB * UU) / 16, DJ / 256), 256, 0, stream>>>(dec, W_dec, b_dec, decp);
    k_joint<<<M_TOTAL / 32, 256, 0, stream>>>(encp, decp, wfcb, b_fc, out);
}